// Round 5
// baseline (662.376 us; speedup 1.0000x reference)
//
#include <hip/hip_runtime.h>

// SGGM: out[131072,768] = concat(h_node[b,i], h_node[b,j], h_edge[b,i,j]) @ W + bias
// B=32, N=128, H=128, E_PER=4096 -> M=131072, K=384, NOUT=768
// R5: two-stage. Stage 1 gathers m into Am[131072][384] bf16 (streaming, latency-
// tolerant). Stage 2 is a gather-free GEMM with BOTH operands via global_load_lds
// (A swizzle applied on the per-lane global source address; LDS stays glds-linear).

#define NNODE 128
#define HDIM  128
#define KDIM  384
#define NOUT  768
#define BM    128
#define BN    128
#define BK    64
#define NKITER 6   // 384/64
#define MTOT  131072

typedef __attribute__((ext_vector_type(4))) float f32x4;
typedef __attribute__((ext_vector_type(8))) short bf16x8;

static __device__ __forceinline__ short f2b(float f) {
    return __builtin_bit_cast(short, (__bf16)f);  // v_cvt RNE
}

static __device__ __forceinline__ void gload_lds16(const void* g, void* l) {
    __builtin_amdgcn_global_load_lds((const __attribute__((address_space(1))) void*)g,
                                     (__attribute__((address_space(3))) void*)l, 16, 0, 0);
}

// WtS: 36 tiles (nb*6+kk), each 1024 chunks of 16B. Chunk c holds
// row = c>>3, kb = (c&7)^(row&7):  bf16(W[kk*64+kb*8+e][nb*128+row]), e=0..7.
// glds-linear LDS placement then satisfies lds_byte(row,kb)=row*128+(kb*16^((row&7)<<4)).
__global__ void prep_kernel(const float* __restrict__ W, short* __restrict__ WtS) {
    int gid  = blockIdx.x * 256 + threadIdx.x;   // 36864 = 36*1024
    int tile = gid >> 10;
    int c    = gid & 1023;
    int nb   = tile / 6, kk = tile - nb * 6;
    int row  = c >> 3;
    int kb   = (c & 7) ^ (row & 7);
    int n    = nb * 128 + row;
    int k0   = kk * 64 + kb * 8;
    short v[8];
    #pragma unroll
    for (int e = 0; e < 8; ++e) v[e] = f2b(W[(k0 + e) * NOUT + n]);
    *(bf16x8*)(WtS + (size_t)gid * 8) = *(bf16x8*)v;
}

// Stage 1: Am[row][k] = bf16(concat(h_node[b,i], h_node[b,j], h_edge[b,i,j]))
// One thread per 8-element chunk: 131072 rows * 48 chunks = 6291456 threads.
__global__ __launch_bounds__(256) void gather_kernel(
    const float* __restrict__ h_node, const float* __restrict__ h_edge,
    const int* __restrict__ pl, short* __restrict__ Am) {
    int cid = blockIdx.x * 256 + threadIdx.x;
    int row = cid / 48;
    int c   = cid - row * 48;          // 0..47
    int b  = pl[3 * row + 0];
    int ii = pl[3 * row + 1];
    int jj = pl[3 * row + 2];
    const float* base;
    int seg = c >> 4;
    if (seg == 0)      base = h_node + (b * NNODE + ii) * HDIM;
    else if (seg == 1) base = h_node + (b * NNODE + jj) * HDIM;
    else               base = h_edge + ((b * NNODE + ii) * NNODE + jj) * HDIM;
    const float* p = base + (c & 15) * 8;
    f32x4 x = *(const f32x4*)p;
    f32x4 y = *(const f32x4*)(p + 4);
    bf16x8 v;
    v[0] = f2b(x[0]); v[1] = f2b(x[1]); v[2] = f2b(x[2]); v[3] = f2b(x[3]);
    v[4] = f2b(y[0]); v[5] = f2b(y[1]); v[6] = f2b(y[2]); v[7] = f2b(y[3]);
    *(bf16x8*)(Am + (size_t)row * KDIM + c * 8) = v;
}

// Stage 2: out = Am @ W^T-prepped + bias. Gather-free; A and B both via glds.
__global__ __launch_bounds__(256) void gemm_kernel(
    const short* __restrict__ Am, const short* __restrict__ WtS,
    const float* __restrict__ bias, float* __restrict__ out) {

    __shared__ __align__(16) short Abuf[2][BM * BK];  // 2x16KB, glds-linear (+src-swz)
    __shared__ __align__(16) short Bbuf[2][BN * BK];  // 2x16KB, glds-linear (+pre-swz)

    const int tid = threadIdx.x;
    const int bid = blockIdx.x;
    // XCD-chunked: 6 n-siblings of each m-block adjacent on the same XCD
    const int xcd = bid & 7;
    const int idx = bid >> 3;            // 0..767
    const int mBase = (xcd * 128 + idx / 6) * BM;
    const int nb    = idx % 6;
    const int nBase = nb * BN;
    const int nb6   = nb * 6;

    const int lane = tid & 63;
    const int wid  = tid >> 6;
    const int wm   = wid & 1;
    const int wn   = wid >> 1;
    const int r    = lane & 15;
    const int g    = lane >> 4;

    f32x4 acc[4][4];
    #pragma unroll
    for (int a = 0; a < 4; ++a)
        #pragma unroll
        for (int b2 = 0; b2 < 4; ++b2)
            acc[a][b2] = (f32x4){0.f, 0.f, 0.f, 0.f};

    auto stageA = [&](int kt, int buf) {
        short* ldsb = &Abuf[buf][0];
        #pragma unroll
        for (int i = 0; i < 4; ++i) {
            int cb0 = wid * 256 + i * 64;       // wave-uniform chunk base
            int c   = cb0 + lane;
            int row = c >> 3;
            int kb  = (c & 7) ^ (row & 7);      // inverse-swizzled source chunk
            const short* src = Am + (size_t)(mBase + row) * KDIM + kt * BK + kb * 8;
            gload_lds16(src, ldsb + cb0 * 8);
        }
    };
    auto stageB = [&](int kt, int buf) {
        const short* src = WtS + (size_t)((nb6 + kt) << 10) * 8;
        short* ldsb = &Bbuf[buf][0];
        #pragma unroll
        for (int i = 0; i < 4; ++i) {
            int cb0 = wid * 256 + i * 64;
            gload_lds16(src + (size_t)(cb0 + lane) * 8, ldsb + cb0 * 8);
        }
    };
    auto compute = [&](int buf) {
        char* Ab = (char*)&Abuf[buf][0];
        char* Bb = (char*)&Bbuf[buf][0];
        #pragma unroll
        for (int ks = 0; ks < 2; ++ks) {
            const int cb = ks * 4 + g;
            bf16x8 ef[4], wf[4];
            #pragma unroll
            for (int mf = 0; mf < 4; ++mf) {
                int row  = wm * 64 + mf * 16 + r;
                int byte = (row * 128 + cb * 16) ^ ((row & 7) << 4);
                ef[mf] = *(const bf16x8*)(Ab + byte);
            }
            #pragma unroll
            for (int nf = 0; nf < 4; ++nf) {
                int row  = wn * 64 + nf * 16 + r;
                int byte = (row * 128 + cb * 16) ^ ((row & 7) << 4);
                wf[nf] = *(const bf16x8*)(Bb + byte);
            }
            #pragma unroll
            for (int nf = 0; nf < 4; ++nf)
                #pragma unroll
                for (int mf = 0; mf < 4; ++mf)
                    acc[nf][mf] = __builtin_amdgcn_mfma_f32_16x16x32_bf16(
                        wf[nf], ef[mf], acc[nf][mf], 0, 0, 0);
        }
    };

    // ---- prologue ----
    stageA(0, 0);
    stageB(0, 0);
    asm volatile("s_waitcnt vmcnt(0)" ::: "memory");
    __syncthreads();

    // ---- main loop: 1 barrier/iter; next tile's glds fly under compute ----
    int cur = 0;
    #pragma unroll
    for (int t = 0; t < NKITER; ++t) {
        if (t + 1 < NKITER) {
            stageA(t + 1, cur ^ 1);
            stageB(t + 1, cur ^ 1);
        }
        __builtin_amdgcn_s_setprio(1);
        compute(cur);
        __builtin_amdgcn_s_setprio(0);
        if (t + 1 < NKITER) {
            asm volatile("s_waitcnt vmcnt(0)" ::: "memory");
            __syncthreads();
        }
        cur ^= 1;
    }

    // ---- epilogue: D row = n_local (g*4+i), col = m_local (r) ----
    #pragma unroll
    for (int nf = 0; nf < 4; ++nf) {
        int n = nBase + wn * 64 + nf * 16 + g * 4;
        f32x4 bb = *(const f32x4*)(bias + n);
        #pragma unroll
        for (int mf = 0; mf < 4; ++mf) {
            int m = mBase + wm * 64 + mf * 16 + r;
            f32x4 v = acc[nf][mf] + bb;
            *(f32x4*)(out + (size_t)m * NOUT + n) = v;
        }
    }
}

extern "C" void kernel_launch(void* const* d_in, const int* in_sizes, int n_in,
                              void* d_out, int out_size, void* d_ws, size_t ws_size,
                              hipStream_t stream) {
    const float* h_node = (const float*)d_in[0];
    const float* h_edge = (const float*)d_in[1];
    const int*   pl     = (const int*)d_in[2];
    const float* W      = (const float*)d_in[3];
    const float* bias   = (const float*)d_in[4];
    float* out = (float*)d_out;
    short* WtS = (short*)d_ws;                          // 589824 B
    short* Am  = (short*)((char*)d_ws + (1 << 20));     // 131072*384*2 = 100663296 B

    prep_kernel<<<144, 256, 0, stream>>>(W, WtS);                        // 36864 chunks
    gather_kernel<<<24576, 256, 0, stream>>>(h_node, h_edge, pl, Am);    // 6291456 chunks
    gemm_kernel<<<1024 * 6, 256, 0, stream>>>(Am, WtS, bias, out);
}